// Round 1
// baseline (283.700 us; speedup 1.0000x reference)
//
#include <hip/hip_runtime.h>
#include <math.h>

#define TWO_PI_F 6.283185307179586f

__device__ __forceinline__ float fast_rcp(float x) { return __builtin_amdgcn_rcpf(x); }

__device__ __forceinline__ float fast_exp(float x) { return __expf(x); }

__device__ __forceinline__ float fast_tanh(float x) {
    // overflow-safe: exp(-2|x|) in (0,1]
    float ax = fabsf(x);
    float t = __expf(-2.0f * ax);
    float r = (1.0f - t) * fast_rcp(1.0f + t);
    return copysignf(r, x);
}

__device__ __forceinline__ float fast_sigmoid(float x) {
    return fast_rcp(1.0f + __expf(-x));
}

__global__ __launch_bounds__(256)
void gsi_kernel(const float* __restrict__ states,
                const float* __restrict__ ew1, const float* __restrict__ eb1,
                const float* __restrict__ ew2, const float* __restrict__ eb2,
                const float* __restrict__ ew3, const float* __restrict__ eb3,
                const float* __restrict__ pw,  const float* __restrict__ pb,
                const float* __restrict__ fwh, const float* __restrict__ fbh,
                const float* __restrict__ fwmu,const float* __restrict__ fbmu,
                const float* __restrict__ fwa, const float* __restrict__ fba,
                float* __restrict__ out, int n)
{
    int i = blockIdx.x * blockDim.x + threadIdx.x;
    if (i >= n) return;

    const float4 s = reinterpret_cast<const float4*>(states)[i];

    // ---- encoder layer 1: 4 -> 64, ReLU ----
    float h1[64];
#pragma unroll
    for (int j = 0; j < 64; ++j) {
        float a = fmaf(s.x, ew1[0 * 64 + j], eb1[j]);
        a = fmaf(s.y, ew1[1 * 64 + j], a);
        a = fmaf(s.z, ew1[2 * 64 + j], a);
        a = fmaf(s.w, ew1[3 * 64 + j], a);
        h1[j] = fmaxf(a, 0.0f);
    }

    // ---- encoder layer 2: 64 -> 32, ReLU ----
    float h2[32];
#pragma unroll
    for (int j = 0; j < 32; ++j) {
        float a = eb2[j];
#pragma unroll
        for (int k = 0; k < 64; ++k) a = fmaf(h1[k], ew2[k * 32 + j], a);
        h2[j] = fmaxf(a, 0.0f);
    }

    // ---- encoder layer 3: 32 -> 8 (linear), then proj 8 -> 3 ----
    float x0, x1, x2;
    {
        float c[8];
#pragma unroll
        for (int j = 0; j < 8; ++j) {
            float a = eb3[j];
#pragma unroll
            for (int k = 0; k < 32; ++k) a = fmaf(h2[k], ew3[k * 8 + j], a);
            c[j] = a;
        }
        float p[3];
#pragma unroll
        for (int j = 0; j < 3; ++j) {
            float a = pb[j];
#pragma unroll
            for (int k = 0; k < 8; ++k) a = fmaf(c[k], pw[k * 3 + j], a);
            p[j] = a;
        }
        x0 = p[0]; x1 = p[1]; x2 = p[2];
    }

    // ---- MAF flow: 10 layers with hard-coded MADE mask structure ----
    // m_h: row0 all ones, row1 only odd cols, row2 zero.
    // m_o: col0 zero, col1 only even rows, col2 all ones.
#pragma unroll
    for (int l = 0; l < 10; ++l) {
        const float* wh  = fwh  + l * 96;   // (3,32)
        const float* bh  = fbh  + l * 32;
        const float* wmu = fwmu + l * 96;   // (32,3)
        const float* bmu = fbmu + l * 3;
        const float* wa  = fwa  + l * 96;   // (32,3)
        const float* ba  = fba  + l * 3;

        float hh[32];
#pragma unroll
        for (int j = 0; j < 32; ++j) {
            float a = fmaf(x0, wh[0 * 32 + j], bh[j]);
            if (j & 1) a = fmaf(x1, wh[1 * 32 + j], a);
            hh[j] = fmaxf(a, 0.0f);
        }

        float mu1 = bmu[1], mu2 = bmu[2];
        float a1 = ba[1], a2 = ba[2];
#pragma unroll
        for (int j = 0; j < 32; ++j) {
            if (!(j & 1)) {
                mu1 = fmaf(hh[j], wmu[j * 3 + 1], mu1);
                a1  = fmaf(hh[j], wa[j * 3 + 1], a1);
            }
            mu2 = fmaf(hh[j], wmu[j * 3 + 2], mu2);
            a2  = fmaf(hh[j], wa[j * 3 + 2], a2);
        }

        float mu0 = bmu[0];
        float t0 = fast_tanh(ba[0]);
        float t1 = fast_tanh(a1);
        float t2 = fast_tanh(a2);

        float y0 = (x0 - mu0) * fast_exp(-t0);
        float y1 = (x1 - mu1) * fast_exp(-t1);
        float y2 = (x2 - mu2) * fast_exp(-t2);

        // flip
        x0 = y2; x1 = y1; x2 = y0;
    }

    // ---- squash + HSV ----
    float u0 = fast_sigmoid(x0);
    float u1 = fast_sigmoid(x1);
    float u2 = fast_sigmoid(x2);

    out[3 * i + 0] = TWO_PI_F * u0;
    out[3 * i + 1] = u1;
    out[3 * i + 2] = u2;
}

extern "C" void kernel_launch(void* const* d_in, const int* in_sizes, int n_in,
                              void* d_out, int out_size, void* d_ws, size_t ws_size,
                              hipStream_t stream) {
    const float* states = (const float*)d_in[0];
    const float* ew1  = (const float*)d_in[1];
    const float* eb1  = (const float*)d_in[2];
    const float* ew2  = (const float*)d_in[3];
    const float* eb2  = (const float*)d_in[4];
    const float* ew3  = (const float*)d_in[5];
    const float* eb3  = (const float*)d_in[6];
    const float* pw   = (const float*)d_in[7];
    const float* pb   = (const float*)d_in[8];
    const float* fwh  = (const float*)d_in[9];
    const float* fbh  = (const float*)d_in[10];
    const float* fwmu = (const float*)d_in[11];
    const float* fbmu = (const float*)d_in[12];
    const float* fwa  = (const float*)d_in[13];
    const float* fba  = (const float*)d_in[14];
    float* out = (float*)d_out;

    int n = in_sizes[0] / 4;  // B rows of STATE_DIM=4
    int grid = (n + 255) / 256;
    gsi_kernel<<<grid, 256, 0, stream>>>(states, ew1, eb1, ew2, eb2, ew3, eb3,
                                         pw, pb, fwh, fbh, fwmu, fbmu, fwa, fba,
                                         out, n);
}

// Round 3
// 192.579 us; speedup vs baseline: 1.4732x; 1.4732x over previous
//
#include <hip/hip_runtime.h>
#include <math.h>

#define TWO_PI_F 6.283185307179586f

typedef __fp16 half2_t __attribute__((ext_vector_type(2)));

// ---- d_ws layout (u32 units) ----
#define OFF_EW1   0       // [64][2]   packed f16 pairs over K of enc_w1
#define OFF_EW2   128     // [32][32]  packed pairs over K of enc_w2
#define OFF_ENCF  1152    // [3][16]   folded (ew3@pw) packed pairs over K
#define OFF_ENCFB 1200    // [3] f32   folded bias (eb3@pw + pb)
#define OFF_FWH   1204    // [10][32]  packed (wh[l][0][j], odd? wh[l][1][j]:0)
#define OFF_FMU1  1524    // [10][16]  packed masked wmu[:,1] pairs (odd k zeroed)
#define OFF_FMU2  1684    // [10][16]  packed wmu[:,2] pairs
#define OFF_FA1   1844    // [10][16]  packed masked wa[:,1] pairs
#define OFF_FA2   2004    // [10][16]  packed wa[:,2] pairs
#define OFF_C0    2164    // [10] f32  exp(-tanh(ba[l][0]))
// total 2174 u32 = 8696 bytes (<< ws_size)

__device__ __forceinline__ unsigned pack2(float a, float b) {
    half2_t h = __builtin_amdgcn_cvt_pkrtz(a, b);
    union { half2_t h; unsigned u; } cvt;
    cvt.h = h;
    return cvt.u;
}

__global__ __launch_bounds__(256)
void gsi_setup(const float* __restrict__ ew1, const float* __restrict__ ew2,
               const float* __restrict__ ew3, const float* __restrict__ eb3,
               const float* __restrict__ pw,  const float* __restrict__ pb,
               const float* __restrict__ fwh, const float* __restrict__ fwmu,
               const float* __restrict__ fwa, const float* __restrict__ fba,
               unsigned* __restrict__ ws)
{
    int t = threadIdx.x;

    // enc_w1 (4,64): pairs over k
    for (int idx = t; idx < 128; idx += 256) {
        int j = idx >> 1, kk = idx & 1;
        ws[OFF_EW1 + idx] = pack2(ew1[(2 * kk) * 64 + j], ew1[(2 * kk + 1) * 64 + j]);
    }
    // enc_w2 (64,32): pairs over k
    for (int idx = t; idx < 1024; idx += 256) {
        int j = idx >> 5, kk = idx & 31;
        ws[OFF_EW2 + idx] = pack2(ew2[(2 * kk) * 32 + j], ew2[(2 * kk + 1) * 32 + j]);
    }
    // folded encoder tail: Wf = ew3(32,8) @ pw(8,3)  -> (32,3), pairs over k
    for (int idx = t; idx < 48; idx += 256) {
        int j = idx >> 4, kk = idx & 15;
        float w0 = 0.f, w1 = 0.f;
        for (int c = 0; c < 8; ++c) {
            w0 += ew3[(2 * kk) * 8 + c] * pw[c * 3 + j];
            w1 += ew3[(2 * kk + 1) * 8 + c] * pw[c * 3 + j];
        }
        ws[OFF_ENCF + idx] = pack2(w0, w1);
    }
    // folded bias: eb3 @ pw + pb
    if (t < 3) {
        float b = pb[t];
        for (int c = 0; c < 8; ++c) b += eb3[c] * pw[c * 3 + t];
        union { float f; unsigned u; } cvt; cvt.f = b;
        ws[OFF_ENCFB + t] = cvt.u;
    }
    // flow hidden weights: pack (wh[l][0][j], odd j ? wh[l][1][j] : 0)
    for (int idx = t; idx < 320; idx += 256) {
        int l = idx >> 5, j = idx & 31;
        float w0 = fwh[l * 96 + 0 * 32 + j];
        float w1 = (j & 1) ? fwh[l * 96 + 1 * 32 + j] : 0.0f;
        ws[OFF_FWH + idx] = pack2(w0, w1);
    }
    // flow output weights, masks folded in. wmu (10,32,3)
    for (int idx = t; idx < 160; idx += 256) {
        int l = idx >> 4, kk = idx & 15;
        // out 1: only even k
        ws[OFF_FMU1 + idx] = pack2(fwmu[l * 96 + (2 * kk) * 3 + 1], 0.0f);
        ws[OFF_FA1  + idx] = pack2(fwa [l * 96 + (2 * kk) * 3 + 1], 0.0f);
        // out 2: all k
        ws[OFF_FMU2 + idx] = pack2(fwmu[l * 96 + (2 * kk) * 3 + 2],
                                   fwmu[l * 96 + (2 * kk + 1) * 3 + 2]);
        ws[OFF_FA2  + idx] = pack2(fwa [l * 96 + (2 * kk) * 3 + 2],
                                   fwa [l * 96 + (2 * kk + 1) * 3 + 2]);
    }
    // per-layer constant scale for dim 0: exp(-tanh(ba[l][0]))
    if (t < 10) {
        union { float f; unsigned u; } cvt;
        cvt.f = expf(-tanhf(fba[t * 3 + 0]));
        ws[OFF_C0 + t] = cvt.u;
    }
}

__device__ __forceinline__ float fast_rcp(float x) { return __builtin_amdgcn_rcpf(x); }

__device__ __forceinline__ float fast_tanh(float x) {
    float ax = fabsf(x);
    float t = __expf(-2.0f * ax);
    float r = (1.0f - t) * fast_rcp(1.0f + t);
    return copysignf(r, x);
}

__device__ __forceinline__ half2_t relu2(float a, float b) {
    half2_t p = __builtin_amdgcn_cvt_pkrtz(a, b);
    half2_t z = {0, 0};
    return __builtin_elementwise_max(p, z);
}

__global__ __launch_bounds__(256)
void gsi_kernel(const float* __restrict__ states,
                const float* __restrict__ eb1, const float* __restrict__ eb2,
                const float* __restrict__ fbh, const float* __restrict__ fbmu,
                const float* __restrict__ fba,
                const unsigned* __restrict__ ws,
                float* __restrict__ out, int n)
{
    int i = blockIdx.x * blockDim.x + threadIdx.x;
    if (i >= n) return;

    const half2_t* ew1p  = (const half2_t*)(ws + OFF_EW1);
    const half2_t* ew2p  = (const half2_t*)(ws + OFF_EW2);
    const half2_t* encfp = (const half2_t*)(ws + OFF_ENCF);
    const float*   encfb = (const float*)  (ws + OFF_ENCFB);
    const half2_t* whp   = (const half2_t*)(ws + OFF_FWH);
    const half2_t* mu1p  = (const half2_t*)(ws + OFF_FMU1);
    const half2_t* mu2p  = (const half2_t*)(ws + OFF_FMU2);
    const half2_t* a1p   = (const half2_t*)(ws + OFF_FA1);
    const half2_t* a2p   = (const half2_t*)(ws + OFF_FA2);
    const float*   c0s   = (const float*)  (ws + OFF_C0);

    const float4 s = reinterpret_cast<const float4*>(states)[i];
    half2_t s01 = __builtin_amdgcn_cvt_pkrtz(s.x, s.y);
    half2_t s23 = __builtin_amdgcn_cvt_pkrtz(s.z, s.w);

    // ---- encoder layer 1: 4 -> 64 (dot2 over K), ReLU, pack ----
    half2_t h1p[32];
#pragma unroll
    for (int j = 0; j < 32; ++j) {
        float a0 = __builtin_amdgcn_fdot2(s01, ew1p[(2 * j) * 2 + 0], eb1[2 * j], false);
        a0 = __builtin_amdgcn_fdot2(s23, ew1p[(2 * j) * 2 + 1], a0, false);
        float a1 = __builtin_amdgcn_fdot2(s01, ew1p[(2 * j + 1) * 2 + 0], eb1[2 * j + 1], false);
        a1 = __builtin_amdgcn_fdot2(s23, ew1p[(2 * j + 1) * 2 + 1], a1, false);
        h1p[j] = relu2(a0, a1);
    }

    // ---- encoder layer 2: 64 -> 32, ReLU, pack ----
    half2_t h2p[16];
#pragma unroll
    for (int j = 0; j < 16; ++j) {
        float a0 = eb2[2 * j];
        float a1 = eb2[2 * j + 1];
#pragma unroll
        for (int kk = 0; kk < 32; ++kk) {
            a0 = __builtin_amdgcn_fdot2(h1p[kk], ew2p[(2 * j) * 32 + kk], a0, false);
            a1 = __builtin_amdgcn_fdot2(h1p[kk], ew2p[(2 * j + 1) * 32 + kk], a1, false);
        }
        h2p[j] = relu2(a0, a1);
    }

    // ---- folded encoder tail: 32 -> 3 ----
    float x0 = encfb[0], x1 = encfb[1], x2 = encfb[2];
#pragma unroll
    for (int kk = 0; kk < 16; ++kk) {
        x0 = __builtin_amdgcn_fdot2(h2p[kk], encfp[0 * 16 + kk], x0, false);
        x1 = __builtin_amdgcn_fdot2(h2p[kk], encfp[1 * 16 + kk], x1, false);
        x2 = __builtin_amdgcn_fdot2(h2p[kk], encfp[2 * 16 + kk], x2, false);
    }

    // ---- MAF flow ----
#pragma unroll
    for (int l = 0; l < 10; ++l) {
        half2_t xp = __builtin_amdgcn_cvt_pkrtz(x0, x1);
        half2_t hp[16];
#pragma unroll
        for (int j = 0; j < 16; ++j) {
            float a0 = __builtin_amdgcn_fdot2(xp, whp[l * 32 + 2 * j],     fbh[l * 32 + 2 * j],     false);
            float a1 = __builtin_amdgcn_fdot2(xp, whp[l * 32 + 2 * j + 1], fbh[l * 32 + 2 * j + 1], false);
            hp[j] = relu2(a0, a1);
        }
        float mu1 = fbmu[l * 3 + 1], mu2 = fbmu[l * 3 + 2];
        float aa1 = fba[l * 3 + 1],  aa2 = fba[l * 3 + 2];
#pragma unroll
        for (int kk = 0; kk < 16; ++kk) {
            mu1 = __builtin_amdgcn_fdot2(hp[kk], mu1p[l * 16 + kk], mu1, false);
            mu2 = __builtin_amdgcn_fdot2(hp[kk], mu2p[l * 16 + kk], mu2, false);
            aa1 = __builtin_amdgcn_fdot2(hp[kk], a1p[l * 16 + kk], aa1, false);
            aa2 = __builtin_amdgcn_fdot2(hp[kk], a2p[l * 16 + kk], aa2, false);
        }
        float t1 = fast_tanh(aa1);
        float t2 = fast_tanh(aa2);
        float y0 = (x0 - fbmu[l * 3 + 0]) * c0s[l];
        float y1 = (x1 - mu1) * __expf(-t1);
        float y2 = (x2 - mu2) * __expf(-t2);
        x0 = y2; x1 = y1; x2 = y0;
    }

    // ---- squash + HSV ----
    float u0 = fast_rcp(1.0f + __expf(-x0));
    float u1 = fast_rcp(1.0f + __expf(-x1));
    float u2 = fast_rcp(1.0f + __expf(-x2));

    out[3 * i + 0] = TWO_PI_F * u0;
    out[3 * i + 1] = u1;
    out[3 * i + 2] = u2;
}

extern "C" void kernel_launch(void* const* d_in, const int* in_sizes, int n_in,
                              void* d_out, int out_size, void* d_ws, size_t ws_size,
                              hipStream_t stream) {
    const float* states = (const float*)d_in[0];
    const float* ew1  = (const float*)d_in[1];
    const float* eb1  = (const float*)d_in[2];
    const float* ew2  = (const float*)d_in[3];
    const float* eb2  = (const float*)d_in[4];
    const float* ew3  = (const float*)d_in[5];
    const float* eb3  = (const float*)d_in[6];
    const float* pw   = (const float*)d_in[7];
    const float* pb   = (const float*)d_in[8];
    const float* fwh  = (const float*)d_in[9];
    const float* fbh  = (const float*)d_in[10];
    const float* fwmu = (const float*)d_in[11];
    const float* fbmu = (const float*)d_in[12];
    const float* fwa  = (const float*)d_in[13];
    const float* fba  = (const float*)d_in[14];
    float* out = (float*)d_out;
    unsigned* ws = (unsigned*)d_ws;

    gsi_setup<<<1, 256, 0, stream>>>(ew1, ew2, ew3, eb3, pw, pb, fwh, fwmu, fwa, fba, ws);

    int n = in_sizes[0] / 4;
    int grid = (n + 255) / 256;
    gsi_kernel<<<grid, 256, 0, stream>>>(states, eb1, eb2, fbh, fbmu, fba, ws, out, n);
}

// Round 4
// 140.271 us; speedup vs baseline: 2.0225x; 1.3729x over previous
//
#include <hip/hip_runtime.h>
#include <math.h>

#define TWO_PI_F 6.283185307179586f

typedef __fp16 half2_t __attribute__((ext_vector_type(2)));
typedef __fp16 half8_t __attribute__((ext_vector_type(8)));
typedef float  f32x4   __attribute__((ext_vector_type(4)));
typedef unsigned u32x2 __attribute__((ext_vector_type(2)));

// ---- d_ws layout (u32 units) ----
#define OFF_EW1   0       // [64][2]   enc_w1 f16 pairs over K
#define OFF_A     128     // [4][64][4] enc2 A-frags (mt*2+kt, lane, reg)
#define OFF_B2I   1152    // [2][64][4] enc2 bias in C-layout (mt, lane, reg) f32
#define OFF_ENCF  1664    // [3][16]   folded (ew3@pw) f16 pairs over K
#define OFF_ENCFB 1712    // [3] f32   folded bias
#define OFF_FWH   1716    // [10][32]  (wh[l][0][j], odd? wh[l][1][j]:0) pairs
#define OFF_FMU1  2036    // [10][16]  masked wmu[:,1] pairs
#define OFF_FMU2  2196    // [10][16]  wmu[:,2] pairs
#define OFF_FA1   2356    // [10][16]  masked wa[:,1] pairs
#define OFF_FA2   2516    // [10][16]  wa[:,2] pairs
#define OFF_C0    2676    // [10] f32  exp(-tanh(ba[l][0]))
// total 2686 u32

// LDS: per-wave slice, 64 rows x 72B (16 u32 data + 2 pad)
#define ROW_STRIDE 72
#define WAVE_SLICE (64 * ROW_STRIDE)   // 4608 B

__device__ __forceinline__ unsigned pack2(float a, float b) {
    half2_t h = __builtin_amdgcn_cvt_pkrtz(a, b);
    union { half2_t h; unsigned u; } cvt;
    cvt.h = h;
    return cvt.u;
}

__global__ __launch_bounds__(256)
void gsi_setup(const float* __restrict__ ew1, const float* __restrict__ ew2,
               const float* __restrict__ eb2,
               const float* __restrict__ ew3, const float* __restrict__ eb3,
               const float* __restrict__ pw,  const float* __restrict__ pb,
               const float* __restrict__ fwh, const float* __restrict__ fwmu,
               const float* __restrict__ fwa, const float* __restrict__ fba,
               unsigned* __restrict__ ws)
{
    int t = threadIdx.x;

    // enc_w1 (4,64): pairs over k
    for (int idx = t; idx < 128; idx += 256) {
        int j = idx >> 1, kk = idx & 1;
        ws[OFF_EW1 + idx] = pack2(ew1[(2 * kk) * 64 + j], ew1[(2 * kk + 1) * 64 + j]);
    }
    // enc2 A-frags: A = W2^T (M=32 feats, K=64 in-feats). k-slot bijection
    // c(q,j) = 32kt + 4q + (j&3) + 16*(j>>2), shared with B-staging in main.
    for (int idx = t; idx < 1024; idx += 256) {
        int r = idx & 3, l = (idx >> 2) & 63, f = idx >> 8;
        int mt = f >> 1, kt = f & 1, q = l >> 4, m = (l & 15) + 16 * mt;
        int j0 = 2 * r;
        int c0 = 32 * kt + 4 * q + (j0 & 3) + 16 * (j0 >> 2);
        // j0, j0+1 share j>>2 and are adjacent in (j&3) -> c1 = c0+1
        ws[OFF_A + idx] = pack2(ew2[c0 * 32 + m], ew2[(c0 + 1) * 32 + m]);
    }
    // enc2 bias in C-layout: feat = 16mt + 4*(l>>4) + reg
    for (int idx = t; idx < 512; idx += 256) {
        int r = idx & 3, l = (idx >> 2) & 63, mt = idx >> 8;
        union { float f; unsigned u; } cvt;
        cvt.f = eb2[16 * mt + 4 * (l >> 4) + r];
        ws[OFF_B2I + idx] = cvt.u;
    }
    // folded encoder tail: Wf = ew3(32,8) @ pw(8,3) -> (32,3), pairs over k
    for (int idx = t; idx < 48; idx += 256) {
        int j = idx >> 4, kk = idx & 15;
        float w0 = 0.f, w1 = 0.f;
        for (int c = 0; c < 8; ++c) {
            w0 += ew3[(2 * kk) * 8 + c] * pw[c * 3 + j];
            w1 += ew3[(2 * kk + 1) * 8 + c] * pw[c * 3 + j];
        }
        ws[OFF_ENCF + idx] = pack2(w0, w1);
    }
    if (t < 3) {
        float b = pb[t];
        for (int c = 0; c < 8; ++c) b += eb3[c] * pw[c * 3 + t];
        union { float f; unsigned u; } cvt; cvt.f = b;
        ws[OFF_ENCFB + t] = cvt.u;
    }
    // flow hidden weights: pack (wh[l][0][j], odd j ? wh[l][1][j] : 0)
    for (int idx = t; idx < 320; idx += 256) {
        int l = idx >> 5, j = idx & 31;
        float w0 = fwh[l * 96 + 0 * 32 + j];
        float w1 = (j & 1) ? fwh[l * 96 + 1 * 32 + j] : 0.0f;
        ws[OFF_FWH + idx] = pack2(w0, w1);
    }
    // flow output weights with MADE masks folded
    for (int idx = t; idx < 160; idx += 256) {
        int l = idx >> 4, kk = idx & 15;
        ws[OFF_FMU1 + idx] = pack2(fwmu[l * 96 + (2 * kk) * 3 + 1], 0.0f);
        ws[OFF_FA1  + idx] = pack2(fwa [l * 96 + (2 * kk) * 3 + 1], 0.0f);
        ws[OFF_FMU2 + idx] = pack2(fwmu[l * 96 + (2 * kk) * 3 + 2],
                                   fwmu[l * 96 + (2 * kk + 1) * 3 + 2]);
        ws[OFF_FA2  + idx] = pack2(fwa [l * 96 + (2 * kk) * 3 + 2],
                                   fwa [l * 96 + (2 * kk + 1) * 3 + 2]);
    }
    if (t < 10) {
        union { float f; unsigned u; } cvt;
        cvt.f = expf(-tanhf(fba[t * 3 + 0]));
        ws[OFF_C0 + t] = cvt.u;
    }
}

__device__ __forceinline__ float fast_rcp(float x) { return __builtin_amdgcn_rcpf(x); }

__device__ __forceinline__ float fast_tanh(float x) {
    float ax = fabsf(x);
    float t = __expf(-2.0f * ax);
    float r = (1.0f - t) * fast_rcp(1.0f + t);
    return copysignf(r, x);
}

__device__ __forceinline__ unsigned relu2u(float a, float b) {
    half2_t p = __builtin_amdgcn_cvt_pkrtz(a, b);
    half2_t z = {0, 0};
    union { half2_t h; unsigned u; } cvt;
    cvt.h = __builtin_elementwise_max(p, z);
    return cvt.u;
}

__global__ __launch_bounds__(256)
void gsi_kernel(const float* __restrict__ states,
                const float* __restrict__ eb1,
                const float* __restrict__ fbh, const float* __restrict__ fbmu,
                const float* __restrict__ fba,
                const unsigned* __restrict__ ws,
                float* __restrict__ out, int n)
{
    __shared__ unsigned smem[4 * WAVE_SLICE / 4];

    int i = blockIdx.x * blockDim.x + threadIdx.x;
    int lane = threadIdx.x & 63;
    int wid = threadIdx.x >> 6;
    int ic = i < n ? i : (n - 1);

    char* base = (char*)smem + wid * WAVE_SLICE;

    const half2_t* ew1p  = (const half2_t*)(ws + OFF_EW1);
    const half8_t* afr   = (const half8_t*)(ws + OFF_A);
    const f32x4*   b2i   = (const f32x4*)  (ws + OFF_B2I);
    const half2_t* encfp = (const half2_t*)(ws + OFF_ENCF);
    const float*   encfb = (const float*)  (ws + OFF_ENCFB);
    const half2_t* whp   = (const half2_t*)(ws + OFF_FWH);
    const half2_t* mu1p  = (const half2_t*)(ws + OFF_FMU1);
    const half2_t* mu2p  = (const half2_t*)(ws + OFF_FMU2);
    const half2_t* a1p   = (const half2_t*)(ws + OFF_FA1);
    const half2_t* a2p   = (const half2_t*)(ws + OFF_FA2);
    const float*   c0s   = (const float*)  (ws + OFF_C0);

    int q = lane >> 4;
    int l15 = lane & 15;

    // prefetch A-frags + bias-init (uniform per wave; L1-hot)
    half8_t aF[4];
#pragma unroll
    for (int f = 0; f < 4; ++f) aF[f] = afr[f * 64 + lane];
    f32x4 acc[2][4];
#pragma unroll
    for (int mt = 0; mt < 2; ++mt) {
        f32x4 binit = b2i[mt * 64 + lane];
#pragma unroll
        for (int nt = 0; nt < 4; ++nt) acc[mt][nt] = binit;
    }

    const float4 s = reinterpret_cast<const float4*>(states)[ic];
    half2_t s01 = __builtin_amdgcn_cvt_pkrtz(s.x, s.y);
    half2_t s23 = __builtin_amdgcn_cvt_pkrtz(s.z, s.w);

    // ---- enc1 (4->64, per-thread dot2) fused with LDS staging of H1^T,
    //      and enc2 (64->32) via MFMA: H2^T = W2^T @ H1^T, K split in 2 halves.
#pragma unroll
    for (int kt = 0; kt < 2; ++kt) {
        // compute 32 H1 cols (16 pairs) of this K-half, write as 8 x b64
#pragma unroll
        for (int u = 0; u < 8; ++u) {
            int p0 = kt * 16 + 2 * u;
            float a0 = __builtin_amdgcn_fdot2(s01, ew1p[(2 * p0) * 2 + 0], eb1[2 * p0], false);
            a0 = __builtin_amdgcn_fdot2(s23, ew1p[(2 * p0) * 2 + 1], a0, false);
            float a1 = __builtin_amdgcn_fdot2(s01, ew1p[(2 * p0 + 1) * 2 + 0], eb1[2 * p0 + 1], false);
            a1 = __builtin_amdgcn_fdot2(s23, ew1p[(2 * p0 + 1) * 2 + 1], a1, false);
            float b0 = __builtin_amdgcn_fdot2(s01, ew1p[(2 * p0 + 2) * 2 + 0], eb1[2 * p0 + 2], false);
            b0 = __builtin_amdgcn_fdot2(s23, ew1p[(2 * p0 + 2) * 2 + 1], b0, false);
            float b1 = __builtin_amdgcn_fdot2(s01, ew1p[(2 * p0 + 3) * 2 + 0], eb1[2 * p0 + 3], false);
            b1 = __builtin_amdgcn_fdot2(s23, ew1p[(2 * p0 + 3) * 2 + 1], b1, false);
            u32x2 wv;
            wv.x = relu2u(a0, a1);
            wv.y = relu2u(b0, b1);
            *(u32x2*)(base + lane * ROW_STRIDE + 8 * u) = wv;
        }
        // B-frags: lane reads rows 16nt+(l15), k-slots c(q,j) matching A-setup
#pragma unroll
        for (int nt = 0; nt < 4; ++nt) {
            u32x2 r0 = *(const u32x2*)(base + (16 * nt + l15) * ROW_STRIDE + 8 * (q + 0));
            u32x2 r1 = *(const u32x2*)(base + (16 * nt + l15) * ROW_STRIDE + 8 * (q + 4));
            union { unsigned u[4]; half8_t v; } bb;
            bb.u[0] = r0.x; bb.u[1] = r0.y; bb.u[2] = r1.x; bb.u[3] = r1.y;
#pragma unroll
            for (int mt = 0; mt < 2; ++mt) {
                acc[mt][nt] = __builtin_amdgcn_mfma_f32_16x16x32_f16(
                    aF[mt * 2 + kt], bb.v, acc[mt][nt], 0, 0, 0);
            }
        }
    }

    // ---- relu + pack H2^T back to per-thread layout via LDS ----
#pragma unroll
    for (int mt = 0; mt < 2; ++mt) {
#pragma unroll
        for (int nt = 0; nt < 4; ++nt) {
            f32x4 v = acc[mt][nt];
            u32x2 wv;
            wv.x = relu2u(v[0] > 0.f ? v[0] : 0.f, v[1] > 0.f ? v[1] : 0.f);
            wv.y = relu2u(v[2] > 0.f ? v[2] : 0.f, v[3] > 0.f ? v[3] : 0.f);
            *(u32x2*)(base + (16 * nt + l15) * ROW_STRIDE + 8 * (q + 4 * mt)) = wv;
        }
    }
    half2_t h2p[16];
#pragma unroll
    for (int d = 0; d < 8; ++d) {
        u32x2 v = *(const u32x2*)(base + lane * ROW_STRIDE + 8 * d);
        union { unsigned u; half2_t h; } c0, c1;
        c0.u = v.x; c1.u = v.y;
        h2p[2 * d] = c0.h;
        h2p[2 * d + 1] = c1.h;
    }

    // ---- folded encoder tail: 32 -> 3 ----
    float x0 = encfb[0], x1 = encfb[1], x2 = encfb[2];
#pragma unroll
    for (int kk = 0; kk < 16; ++kk) {
        x0 = __builtin_amdgcn_fdot2(h2p[kk], encfp[0 * 16 + kk], x0, false);
        x1 = __builtin_amdgcn_fdot2(h2p[kk], encfp[1 * 16 + kk], x1, false);
        x2 = __builtin_amdgcn_fdot2(h2p[kk], encfp[2 * 16 + kk], x2, false);
    }

    // ---- MAF flow ----
#pragma unroll
    for (int l = 0; l < 10; ++l) {
        half2_t xp = __builtin_amdgcn_cvt_pkrtz(x0, x1);
        half2_t hp[16];
#pragma unroll
        for (int j = 0; j < 16; ++j) {
            float a0 = __builtin_amdgcn_fdot2(xp, whp[l * 32 + 2 * j],     fbh[l * 32 + 2 * j],     false);
            float a1 = __builtin_amdgcn_fdot2(xp, whp[l * 32 + 2 * j + 1], fbh[l * 32 + 2 * j + 1], false);
            half2_t p = __builtin_amdgcn_cvt_pkrtz(a0, a1);
            half2_t z = {0, 0};
            hp[j] = __builtin_elementwise_max(p, z);
        }
        float mu1 = fbmu[l * 3 + 1], mu2 = fbmu[l * 3 + 2];
        float aa1 = fba[l * 3 + 1],  aa2 = fba[l * 3 + 2];
#pragma unroll
        for (int kk = 0; kk < 16; ++kk) {
            mu1 = __builtin_amdgcn_fdot2(hp[kk], mu1p[l * 16 + kk], mu1, false);
            mu2 = __builtin_amdgcn_fdot2(hp[kk], mu2p[l * 16 + kk], mu2, false);
            aa1 = __builtin_amdgcn_fdot2(hp[kk], a1p[l * 16 + kk], aa1, false);
            aa2 = __builtin_amdgcn_fdot2(hp[kk], a2p[l * 16 + kk], aa2, false);
        }
        float t1 = fast_tanh(aa1);
        float t2 = fast_tanh(aa2);
        float y0 = (x0 - fbmu[l * 3 + 0]) * c0s[l];
        float y1 = (x1 - mu1) * __expf(-t1);
        float y2 = (x2 - mu2) * __expf(-t2);
        x0 = y2; x1 = y1; x2 = y0;
    }

    // ---- squash + HSV ----
    float u0 = fast_rcp(1.0f + __expf(-x0));
    float u1 = fast_rcp(1.0f + __expf(-x1));
    float u2 = fast_rcp(1.0f + __expf(-x2));

    if (i < n) {
        out[3 * i + 0] = TWO_PI_F * u0;
        out[3 * i + 1] = u1;
        out[3 * i + 2] = u2;
    }
}

extern "C" void kernel_launch(void* const* d_in, const int* in_sizes, int n_in,
                              void* d_out, int out_size, void* d_ws, size_t ws_size,
                              hipStream_t stream) {
    const float* states = (const float*)d_in[0];
    const float* ew1  = (const float*)d_in[1];
    const float* eb1  = (const float*)d_in[2];
    const float* ew2  = (const float*)d_in[3];
    const float* eb2  = (const float*)d_in[4];
    const float* ew3  = (const float*)d_in[5];
    const float* eb3  = (const float*)d_in[6];
    const float* pw   = (const float*)d_in[7];
    const float* pb   = (const float*)d_in[8];
    const float* fwh  = (const float*)d_in[9];
    const float* fbh  = (const float*)d_in[10];
    const float* fwmu = (const float*)d_in[11];
    const float* fbmu = (const float*)d_in[12];
    const float* fwa  = (const float*)d_in[13];
    const float* fba  = (const float*)d_in[14];
    float* out = (float*)d_out;
    unsigned* ws = (unsigned*)d_ws;

    gsi_setup<<<1, 256, 0, stream>>>(ew1, ew2, eb2, ew3, eb3, pw, pb,
                                     fwh, fwmu, fwa, fba, ws);

    int n = in_sizes[0] / 4;
    int grid = (n + 255) / 256;
    gsi_kernel<<<grid, 256, 0, stream>>>(states, eb1, fbh, fbmu, fba, ws, out, n);
}